// Round 1
// baseline (1056.917 us; speedup 1.0000x reference)
//
#include <hip/hip_runtime.h>

typedef _Float16 f16;
typedef __attribute__((ext_vector_type(4))) _Float16 f16x4;
typedef __attribute__((ext_vector_type(8))) _Float16 f16x8;
typedef __attribute__((ext_vector_type(4))) float f32x4;

#define NB 4
#define SS 2048
#define DM 768
#define NH 12
#define HDIM 64
#define NBH 48
#define MROWS 8192

// workspace layout (bytes)
#define XH_OFF   0ull            // x in fp16       [8192,768]          12582912
#define WT_OFF   12582912ull     // Wq,Wk,Wv,Wo transposed fp16 [4][768][768]  4718592
#define QH_OFF   17301504ull     // Q fp16 [B,H,S,D] (pre-scaled)       12582912
#define KH_OFF   29884416ull     // K fp16 [B,H,S,D]                    12582912
#define VH_OFF   42467328ull     // V fp16 [B,H,S,D]                    12582912
#define VT_OFF   55050240ull     // V^T fp16 [B,H,D,S]                  12582912
#define AO_OFF   67633152ull     // attention out fp16 [B,S,768]        12582912

__device__ __forceinline__ void async_copy16(const void* g, void* l) {
  // LDS dest must be the WAVE-UNIFORM base; HW adds lane*16 bytes.
  __builtin_amdgcn_global_load_lds((const __attribute__((address_space(1))) void*)g,
                                   (__attribute__((address_space(3))) void*)l, 16, 0, 0);
}

// ---------------- x -> fp16 ----------------
__global__ void k_cvt_x(const float* __restrict__ x, f16* __restrict__ xh, int n4) {
  int i = blockIdx.x * 256 + threadIdx.x;
  if (i >= n4) return;
  float4 v = ((const float4*)x)[i];
  f16x4 o;
  o.x = (f16)v.x; o.y = (f16)v.y; o.z = (f16)v.z; o.w = (f16)v.w;
  ((f16x4*)xh)[i] = o;
}

// ---------------- weights -> fp16, transposed to [N][K] ----------------
__global__ void k_wt(const float* __restrict__ Wq, const float* __restrict__ Wk,
                     const float* __restrict__ Wv, const float* __restrict__ Wo,
                     f16* __restrict__ wt) {
  __shared__ float t[32][33];
  const int w = blockIdx.z;
  const float* W = (w == 0) ? Wq : (w == 1) ? Wk : (w == 2) ? Wv : Wo;
  const int bx = blockIdx.x * 32, by = blockIdx.y * 32;
  const int tx = threadIdx.x, ty = threadIdx.y;
  t[ty][tx] = W[(size_t)(by + ty) * DM + bx + tx];
  __syncthreads();
  wt[(size_t)w * DM * DM + (size_t)(bx + ty) * DM + by + tx] = (f16)t[tx][ty];
}

// ---------------- 128x128 MFMA GEMM: C = A[8192,768] @ W ----------------
// MODE 0: A=xh, weights {Wq,Wk,Wv} (blockIdx.y = w*6+ntile) -> Qh(*0.125)/Kh/Vh in [B,H,S,D]
// MODE 1: A=AO,  weight Wo (blockIdx.y = ntile)             -> fp32 out [8192,768]
template<int MODE>
__global__ __launch_bounds__(256) void k_gemm(const f16* __restrict__ A,
                                              const f16* __restrict__ Wt,
                                              float* __restrict__ outF,
                                              f16* __restrict__ Qh,
                                              f16* __restrict__ Kh,
                                              f16* __restrict__ Vh) {
  __shared__ f16 Al[128 * 32];
  __shared__ f16 Bl[128 * 32];
  const int tid = threadIdx.x, lane = tid & 63, wid = tid >> 6;
  const int mt = blockIdx.x;
  int w, ntile;
  if (MODE == 0) { w = blockIdx.y / 6; ntile = blockIdx.y % 6; }
  else           { w = 3;              ntile = blockIdx.y; }
  const f16* Wb = Wt + (size_t)w * DM * DM;

  f32x4 acc[4][4] = {};
  const int wr = (wid >> 1) * 64, wc = (wid & 1) * 64;

  const int r0 = tid >> 2, c8 = (tid & 3) * 8;
  const f16* As0 = A  + (size_t)(mt * 128 + r0) * DM + c8;
  const f16* As1 = A  + (size_t)(mt * 128 + r0 + 64) * DM + c8;
  const f16* Bs0 = Wb + (size_t)(ntile * 128 + r0) * DM + c8;
  const f16* Bs1 = Wb + (size_t)(ntile * 128 + r0 + 64) * DM + c8;
  f16* Ald0 = &Al[wid * 512];          f16* Ald1 = &Al[2048 + wid * 512];
  f16* Bld0 = &Bl[wid * 512];          f16* Bld1 = &Bl[2048 + wid * 512];

  for (int k0 = 0; k0 < DM; k0 += 32) {
    __syncthreads();
    async_copy16(As0 + k0, Ald0);
    async_copy16(As1 + k0, Ald1);
    async_copy16(Bs0 + k0, Bld0);
    async_copy16(Bs1 + k0, Bld1);
    __syncthreads();
    f16x8 af[4], bfr[4];
#pragma unroll
    for (int r = 0; r < 4; ++r)
      af[r] = *(const f16x8*)&Al[(wr + r * 16 + (lane & 15)) * 32 + (lane >> 4) * 8];
#pragma unroll
    for (int c = 0; c < 4; ++c)
      bfr[c] = *(const f16x8*)&Bl[(wc + c * 16 + (lane & 15)) * 32 + (lane >> 4) * 8];
#pragma unroll
    for (int r = 0; r < 4; ++r)
#pragma unroll
      for (int c = 0; c < 4; ++c)
        acc[r][c] = __builtin_amdgcn_mfma_f32_16x16x32_f16(af[r], bfr[c], acc[r][c], 0, 0, 0);
  }

#pragma unroll
  for (int r = 0; r < 4; ++r)
#pragma unroll
    for (int c = 0; c < 4; ++c)
#pragma unroll
      for (int i = 0; i < 4; ++i) {
        const int gm = mt * 128 + wr + r * 16 + (lane >> 4) * 4 + i;
        const int gn = ntile * 128 + wc + c * 16 + (lane & 15);
        const float v = acc[r][c][i];
        if (MODE == 1) {
          outF[(size_t)gm * DM + gn] = v;
        } else {
          const int b = gm >> 11, s = gm & 2047;
          const int h = gn >> 6, d = gn & 63;
          const size_t idx = ((size_t)(b * NH + h) * SS + s) * HDIM + d;
          if (w == 0)      Qh[idx] = (f16)(v * 0.125f);  // 1/sqrt(64)
          else if (w == 1) Kh[idx] = (f16)v;
          else             Vh[idx] = (f16)v;
        }
      }
}

// ---------------- V [B,H,S,D] -> V^T [B,H,D,S] ----------------
__global__ void k_vt(const f16* __restrict__ Vh, f16* __restrict__ Vt) {
  const int lane = threadIdx.x & 63, wid = threadIdx.x >> 6;
  const int s = blockIdx.x * 64 + lane;
  const int bh = blockIdx.y;
#pragma unroll
  for (int p = 0; p < 2; ++p) {
    const int d0 = wid * 16 + p * 8;
    f16x8 v = *(const f16x8*)&Vh[((size_t)bh * SS + s) * HDIM + d0];
#pragma unroll
    for (int q = 0; q < 8; ++q)
      Vt[((size_t)bh * HDIM + d0 + q) * SS + s] = v[q];  // 64 lanes -> 128B contiguous
  }
}

// ---------------- fused attention ----------------
// grid (16 q-tiles, 48 bh), 256 threads = 4 waves x 32 q-rows.
// Per kv-chunk (64): stage K[64s x 64d], Vt[64d x 64s] in LDS (XOR-swizzled source),
// QK^T via mfma 16x16x32, store raw logits, online softmax, P->LDS(stride 72)->PV.
__global__ __launch_bounds__(256) void k_attn(const f16* __restrict__ Qh,
                                              const f16* __restrict__ Kh,
                                              const f16* __restrict__ Vt,
                                              const float* __restrict__ qm,
                                              float* __restrict__ logits,
                                              f16* __restrict__ AO) {
  __shared__ f16 Kl[64 * 64];
  __shared__ f16 Vl[64 * 64];
  __shared__ f16 Pl[4][16 * 72];
  const int tid = threadIdx.x, lane = tid & 63, wid = tid >> 6;
  const int qt = blockIdx.x, bh = blockIdx.y;
  const int b = bh / NH, h = bh - b * NH;
  const int q0 = qt * 128 + wid * 32;

  // Q fragments (A-operand: row = lane&15, k contiguous)
  f16x8 qf[2][2];
#pragma unroll
  for (int rt = 0; rt < 2; ++rt)
#pragma unroll
    for (int ks = 0; ks < 2; ++ks)
      qf[rt][ks] = *(const f16x8*)&Qh[((size_t)bh * SS + q0 + rt * 16 + (lane & 15)) * HDIM +
                                      ks * 32 + (lane >> 4) * 8];

  float qmq[2][4];
#pragma unroll
  for (int rt = 0; rt < 2; ++rt)
#pragma unroll
    for (int i = 0; i < 4; ++i)
      qmq[rt][i] = qm[b * SS + q0 + rt * 16 + (lane >> 4) * 4 + i];

  float mrun[2][4], lrun[2][4];
#pragma unroll
  for (int rt = 0; rt < 2; ++rt)
#pragma unroll
    for (int i = 0; i < 4; ++i) { mrun[rt][i] = -3.0e38f; lrun[rt][i] = 0.f; }
  f32x4 o[2][4] = {};

  float* const logbase = logits + (size_t)bh * SS * SS;
  const char* const Kbase = (const char*)Kh + (size_t)bh * SS * HDIM * 2;
  const char* const Vbase = (const char*)Vt + (size_t)bh * HDIM * SS * 2;
  const int r0s = tid >> 3;            // staging row for j=0
  const int wb0 = (tid & 7) * 16;      // within-row byte

  for (int c = 0; c < 32; ++c) {
    __syncthreads();
#pragma unroll
    for (int j = 0; j < 2; ++j) {
      const int r = r0s + j * 32;
      const int swb = wb0 ^ ((r & 7) << 4);   // pre-swizzle SOURCE, LDS stays linear (G21)
      async_copy16(Kbase + (size_t)(c * 64 + r) * 128 + swb,
                   (char*)Kl + wid * 1024 + j * 4096);
      async_copy16(Vbase + (size_t)r * 4096 + c * 128 + swb,
                   (char*)Vl + wid * 1024 + j * 4096);
    }
    __syncthreads();

    f16x8 kf[4][2], vf[4][2];
#pragma unroll
    for (int t = 0; t < 4; ++t)
#pragma unroll
      for (int ks = 0; ks < 2; ++ks) {
        const int row = t * 16 + (lane & 15);
        const int byt = row * 128 + ((ks * 64 + (lane >> 4) * 16) ^ ((row & 7) << 4));
        kf[t][ks] = *(const f16x8*)((const char*)Kl + byt);
        vf[t][ks] = *(const f16x8*)((const char*)Vl + byt);
      }

    f32x4 sacc[2][4];
#pragma unroll
    for (int rt = 0; rt < 2; ++rt)
#pragma unroll
      for (int ct = 0; ct < 4; ++ct) {
        f32x4 z = {};
        z = __builtin_amdgcn_mfma_f32_16x16x32_f16(qf[rt][0], kf[ct][0], z, 0, 0, 0);
        sacc[rt][ct] = __builtin_amdgcn_mfma_f32_16x16x32_f16(qf[rt][1], kf[ct][1], z, 0, 0, 0);
      }

    // raw logits out (pre-mask, matches logits_raw)
#pragma unroll
    for (int rt = 0; rt < 2; ++rt)
#pragma unroll
      for (int ct = 0; ct < 4; ++ct)
#pragma unroll
        for (int i = 0; i < 4; ++i) {
          const int gq = q0 + rt * 16 + (lane >> 4) * 4 + i;
          const int gk = c * 64 + ct * 16 + (lane & 15);
          logbase[(size_t)gq * SS + gk] = sacc[rt][ct][i];
        }

    float qmk[4];
#pragma unroll
    for (int ct = 0; ct < 4; ++ct) qmk[ct] = qm[b * SS + c * 64 + ct * 16 + (lane & 15)];

#pragma unroll
    for (int rt = 0; rt < 2; ++rt) {
      float p[4][4];
      float pm[4] = {-3.0e38f, -3.0e38f, -3.0e38f, -3.0e38f};
#pragma unroll
      for (int ct = 0; ct < 4; ++ct)
#pragma unroll
        for (int i = 0; i < 4; ++i) {
          const float sb = sacc[rt][ct][i] - 100000.f * (1.f - qmq[rt][i] * qmk[ct]);
          p[ct][i] = sb;
          pm[i] = fmaxf(pm[i], sb);
        }
#pragma unroll
      for (int off = 1; off < 16; off <<= 1)
#pragma unroll
        for (int i = 0; i < 4; ++i) pm[i] = fmaxf(pm[i], __shfl_xor(pm[i], off));

      float scal[4];
#pragma unroll
      for (int i = 0; i < 4; ++i) {
        const float mnew = fmaxf(mrun[rt][i], pm[i]);
        scal[i] = __expf(mrun[rt][i] - mnew);
        mrun[rt][i] = mnew;
      }
#pragma unroll
      for (int ct = 0; ct < 4; ++ct)
#pragma unroll
        for (int i = 0; i < 4; ++i) p[ct][i] = __expf(p[ct][i] - mrun[rt][i]);

      float rs[4];
#pragma unroll
      for (int i = 0; i < 4; ++i) rs[i] = p[0][i] + p[1][i] + p[2][i] + p[3][i];
#pragma unroll
      for (int off = 1; off < 16; off <<= 1)
#pragma unroll
        for (int i = 0; i < 4; ++i) rs[i] += __shfl_xor(rs[i], off);
#pragma unroll
      for (int i = 0; i < 4; ++i) lrun[rt][i] = lrun[rt][i] * scal[i] + rs[i];
#pragma unroll
      for (int dt = 0; dt < 4; ++dt)
#pragma unroll
        for (int i = 0; i < 4; ++i) o[rt][dt][i] *= scal[i];

      // P -> per-wave LDS (stride 72 f16 = 144B: 2-way banks only), then A-frag reads
      f16* pw = Pl[wid];
#pragma unroll
      for (int ct = 0; ct < 4; ++ct)
#pragma unroll
        for (int i = 0; i < 4; ++i)
          pw[((lane >> 4) * 4 + i) * 72 + ct * 16 + (lane & 15)] = (f16)p[ct][i];
      asm volatile("s_waitcnt lgkmcnt(0)" ::: "memory");  // same-wave write->read, in-order DS
      const f16x8 pf0 = *(const f16x8*)&pw[(lane & 15) * 72 + (lane >> 4) * 8];
      const f16x8 pf1 = *(const f16x8*)&pw[(lane & 15) * 72 + 32 + (lane >> 4) * 8];
#pragma unroll
      for (int dt = 0; dt < 4; ++dt) {
        o[rt][dt] = __builtin_amdgcn_mfma_f32_16x16x32_f16(pf0, vf[dt][0], o[rt][dt], 0, 0, 0);
        o[rt][dt] = __builtin_amdgcn_mfma_f32_16x16x32_f16(pf1, vf[dt][1], o[rt][dt], 0, 0, 0);
      }
    }
  }

#pragma unroll
  for (int rt = 0; rt < 2; ++rt)
#pragma unroll
    for (int i = 0; i < 4; ++i) {
      const float inv = 1.0f / lrun[rt][i];
      const int gq = q0 + rt * 16 + (lane >> 4) * 4 + i;
#pragma unroll
      for (int dt = 0; dt < 4; ++dt)
        AO[((size_t)b * SS + gq) * DM + h * HDIM + dt * 16 + (lane & 15)] =
            (f16)(o[rt][dt][i] * inv);
    }
}

extern "C" void kernel_launch(void* const* d_in, const int* in_sizes, int n_in,
                              void* d_out, int out_size, void* d_ws, size_t ws_size,
                              hipStream_t stream) {
  const float* x  = (const float*)d_in[0];
  const float* qm = (const float*)d_in[1];
  const float* Wq = (const float*)d_in[2];
  const float* Wk = (const float*)d_in[3];
  const float* Wv = (const float*)d_in[4];
  const float* Wo = (const float*)d_in[5];
  float* out    = (float*)d_out;            // [4,2048,768]
  float* logits = out + 6291456;            // [4,12,2048,2048]

  char* ws = (char*)d_ws;
  f16* xh = (f16*)(ws + XH_OFF);
  f16* wt = (f16*)(ws + WT_OFF);
  f16* qh = (f16*)(ws + QH_OFF);
  f16* kh = (f16*)(ws + KH_OFF);
  f16* vh = (f16*)(ws + VH_OFF);
  f16* vt = (f16*)(ws + VT_OFF);
  f16* ao = (f16*)(ws + AO_OFF);

  const int n4 = MROWS * DM / 4;  // 1572864
  k_cvt_x<<<(n4 + 255) / 256, 256, 0, stream>>>(x, xh, n4);
  k_wt<<<dim3(24, 24, 4), dim3(32, 32), 0, stream>>>(Wq, Wk, Wv, Wo, wt);
  k_gemm<0><<<dim3(64, 18), 256, 0, stream>>>(xh, wt, nullptr, qh, kh, vh);
  k_vt<<<dim3(32, 48), 256, 0, stream>>>(vh, vt);
  k_attn<<<dim3(16, 48), 256, 0, stream>>>(qh, kh, vt, qm, logits, ao);
  k_gemm<1><<<dim3(64, 6), 256, 0, stream>>>(ao, wt, out, nullptr, nullptr, nullptr);
}